// Round 2
// baseline (791.194 us; speedup 1.0000x reference)
//
#include <hip/hip_runtime.h>

#define TT   2048
#define DD   4096
#define NH   32
#define NKVH 8
#define HDM  128
#define KD   4096
#define NQKV 6144

typedef unsigned short u16;
typedef short v8s __attribute__((ext_vector_type(8)));
typedef float v4f __attribute__((ext_vector_type(4)));

__device__ __forceinline__ u16 f2bf(float f) {
    unsigned u = __builtin_bit_cast(unsigned, f);
    u += 0x7fffu + ((u >> 16) & 1u);   // round-to-nearest-even
    return (u16)(u >> 16);
}
__device__ __forceinline__ float bf2f(u16 h) {
    return __builtin_bit_cast(float, ((unsigned)h) << 16);
}
__device__ __forceinline__ void gl2lds16(const void* g, void* l) {
    // async global->LDS, 16B/lane; LDS dest = wave-uniform base + lane*16
    using gv = const __attribute__((address_space(1))) void;
    using lv = __attribute__((address_space(3))) void;
    __builtin_amdgcn_global_load_lds((gv*)g, (lv*)l, 16, 0, 0);
}

// ---------------- cast hidden fp32 -> bf16 ----------------
__global__ __launch_bounds__(256) void cast_bf_kernel(const float* __restrict__ in,
                                                      u16* __restrict__ out) {
    size_t i = ((size_t)blockIdx.x * 256 + threadIdx.x) * 8;
    float4 a = *(const float4*)&in[i];
    float4 b = *(const float4*)&in[i + 4];
    v8s tv;
    tv[0] = (short)f2bf(a.x); tv[1] = (short)f2bf(a.y);
    tv[2] = (short)f2bf(a.z); tv[3] = (short)f2bf(a.w);
    tv[4] = (short)f2bf(b.x); tv[5] = (short)f2bf(b.y);
    tv[6] = (short)f2bf(b.z); tv[7] = (short)f2bf(b.w);
    *(v8s*)&out[i] = tv;
}

// -------- transpose + cast slice: out[n][k] = bf16(in[k][n_off + n]) --------
__global__ __launch_bounds__(256) void transpose_cast_kernel(const float* __restrict__ in,
                                                             u16* __restrict__ out,
                                                             int K, int N, int n_off) {
    __shared__ float tile[64][65];
    int n0 = blockIdx.x * 64, k0 = blockIdx.y * 64;
    int t = threadIdx.x;
    int rc = t >> 4;
    int cc = (t & 15) * 4;
#pragma unroll
    for (int p = 0; p < 4; ++p) {
        int k = p * 16 + rc;
        float4 v = *(const float4*)&in[(size_t)(k0 + k) * N + n_off + n0 + cc];
        tile[k][cc] = v.x; tile[k][cc + 1] = v.y;
        tile[k][cc + 2] = v.z; tile[k][cc + 3] = v.w;
    }
    __syncthreads();
    int rn = t >> 3;
    int ck = (t & 7) * 8;
#pragma unroll
    for (int p = 0; p < 2; ++p) {
        int n = p * 32 + rn;
        v8s tv;
#pragma unroll
        for (int j = 0; j < 8; ++j) tv[j] = (short)f2bf(tile[ck + j][n]);
        *(v8s*)&out[(size_t)(n0 + n) * K + k0 + ck] = tv;
    }
}

// ---------------- RoPE cos/sin table: [T][64] ----------------
__global__ __launch_bounds__(256) void rope_tab_kernel(const int* __restrict__ positions,
                                                       float* __restrict__ cosT,
                                                       float* __restrict__ sinT) {
    int idx = blockIdx.x * 256 + threadIdx.x;   // T*64 threads
    int tp = idx >> 6, i = idx & 63;
    float invf = exp2f(-(float)i * 0.31143075889569023f);  // log2(1e6)/64
    float f = (float)positions[tp] * invf;
    cosT[idx] = cosf(f);
    sinT[idx] = sinf(f);
}

// ---------------- GEMM: C[M,:] = A[M,K]bf16 @ Bt_slice[N,K]^T bf16 ----------------
// Bt is a column-slice, slice-local rows; nblk_off = global 128-col block offset.
// MODE 0: fp32 C store at global cols.  MODE 1: fused QK-norm + RoPE -> Q/K/Vt.
template <int MODE>
__global__ __launch_bounds__(256) void gemm_bt_kernel(
    const u16* __restrict__ A, const u16* __restrict__ Bt, float* __restrict__ C, int N,
    int nblk_off,
    const float* __restrict__ qw, const float* __restrict__ kw,
    const float* __restrict__ cosT, const float* __restrict__ sinT,
    u16* __restrict__ Qb, u16* __restrict__ Kb, u16* __restrict__ Vt)
{
    __shared__ __align__(16) u16 smem[16896];   // stage: A[128][64]+B[128][64]; epilogue: Ct[128][132]
    u16* As = smem;
    u16* Bs = smem + 8192;
    int tid = threadIdx.x;
    int wave = tid >> 6, lane = tid & 63;
    int quad = lane >> 4, l15 = lane & 15;
    int wm = wave >> 1, wn = wave & 1;
    int m0 = blockIdx.y * 128, n0 = blockIdx.x * 128;   // n0 is slice-local

    v4f acc[4][4];
    v4f z4 = {0.f, 0.f, 0.f, 0.f};
#pragma unroll
    for (int mi = 0; mi < 4; ++mi)
#pragma unroll
        for (int ni = 0; ni < 4; ++ni) acc[mi][ni] = z4;

    int srow = lane >> 3;
    int scol = (lane & 7) * 8;
    const u16* Ag = &A[(size_t)m0 * KD + scol];
    const u16* Bg = &Bt[(size_t)n0 * KD + scol];

    for (int k0 = 0; k0 < KD; k0 += 64) {
        __syncthreads();
#pragma unroll
        for (int c = 0; c < 4; ++c) {
            int ch = wave * 4 + c;
            int row = ch * 8 + srow;
            gl2lds16(&Ag[(size_t)row * KD + k0], &As[ch * 512]);
            gl2lds16(&Bg[(size_t)row * KD + k0], &Bs[ch * 512]);
        }
        __syncthreads();
#pragma unroll
        for (int ks = 0; ks < 2; ++ks) {
            v8s af[4], bfr[4];
#pragma unroll
            for (int mi = 0; mi < 4; ++mi)
                af[mi] = *(const v8s*)&As[(wm * 64 + mi * 16 + l15) * 64 + ks * 32 + quad * 8];
#pragma unroll
            for (int ni = 0; ni < 4; ++ni)
                bfr[ni] = *(const v8s*)&Bs[(wn * 64 + ni * 16 + l15) * 64 + ks * 32 + quad * 8];
#pragma unroll
            for (int mi = 0; mi < 4; ++mi)
#pragma unroll
                for (int ni = 0; ni < 4; ++ni)
                    acc[mi][ni] = __builtin_amdgcn_mfma_f32_16x16x32_bf16(
                        af[mi], bfr[ni], acc[mi][ni], 0, 0, 0);
        }
    }

    if (MODE == 0) {
        int ng0 = (nblk_off + blockIdx.x) * 128;
#pragma unroll
        for (int mi = 0; mi < 4; ++mi)
#pragma unroll
            for (int ni = 0; ni < 4; ++ni)
#pragma unroll
                for (int r = 0; r < 4; ++r)
                    C[(size_t)(m0 + wm * 64 + mi * 16 + quad * 4 + r) * N +
                      (ng0 + wn * 64 + ni * 16 + l15)] = acc[mi][ni][r];
    } else {
        // ---- fused epilogue: this block's 128 cols == one head ----
        __syncthreads();
        u16* Ct = smem;   // [128][132] bf16, padded stride
#pragma unroll
        for (int mi = 0; mi < 4; ++mi)
#pragma unroll
            for (int ni = 0; ni < 4; ++ni)
#pragma unroll
                for (int r = 0; r < 4; ++r)
                    Ct[(wm * 64 + mi * 16 + quad * 4 + r) * 132 + wn * 64 + ni * 16 + l15] =
                        f2bf(acc[mi][ni][r]);
        __syncthreads();
        int head = nblk_off + blockIdx.x;    // 0..31 q, 32..39 k, 40..47 v
        int t0 = blockIdx.y * 128;
        if (head < 40) {
            if (tid < 128) {
                int row = tid;
                const float* w = (head < 32) ? qw : kw;
                float ss = 0.f;
                for (int i = 0; i < 128; ++i) {
                    float x = bf2f(Ct[row * 132 + i]);
                    ss += x * x;
                }
                float rs = rsqrtf(ss * (1.0f / 128.0f) + 1e-6f);
                int ti = t0 + row;
                for (int i = 0; i < 64; ++i) {
                    float x1 = bf2f(Ct[row * 132 + i]) * rs * w[i];
                    float x2 = bf2f(Ct[row * 132 + 64 + i]) * rs * w[64 + i];
                    float c = cosT[ti * 64 + i], s = sinT[ti * 64 + i];
                    Ct[row * 132 + i]      = f2bf(x1 * c - x2 * s);
                    Ct[row * 132 + 64 + i] = f2bf(x2 * c + x1 * s);
                }
            }
            __syncthreads();
            u16* dst = (head < 32) ? &Qb[((size_t)head * TT + t0) * HDM]
                                   : &Kb[((size_t)(head - 32) * TT + t0) * HDM];
            for (int cix = tid; cix < 128 * 16; cix += 256) {
                int row = cix >> 4, part = (cix & 15) * 8;
                v8s tv;
#pragma unroll
                for (int j = 0; j < 8; ++j) tv[j] = (short)Ct[row * 132 + part + j];
                *(v8s*)&dst[row * HDM + part] = tv;
            }
        } else {
            // V head: write transposed Vt[kv][hd][t]
            int kvh = head - 40;
            if (tid < 128) {
                int hd = tid;
#pragma unroll
                for (int tb = 0; tb < 16; ++tb) {
                    v8s tv;
#pragma unroll
                    for (int j = 0; j < 8; ++j) tv[j] = (short)Ct[(tb * 8 + j) * 132 + hd];
                    *(v8s*)&Vt[((size_t)kvh * HDM + hd) * TT + t0 + tb * 8] = tv;
                }
            }
        }
    }
}

// ---------------- flash attention (causal, GQA) ----------------
// block = (q-tile of 64, head); 4 waves x 16 q-rows; s-tiles of 64
__global__ __launch_bounds__(256) void attn_kernel(
    const u16* __restrict__ Qb, const u16* __restrict__ Kb,
    const u16* __restrict__ Vt, u16* __restrict__ Ob)
{
    __shared__ __align__(16) u16 Kl[64 * 128];   // [s][hd]
    __shared__ __align__(16) u16 Vl[128 * 64];   // [hd][s]
    __shared__ __align__(16) u16 Pl[4 * 16 * 72];  // per-wave P, padded stride 72
    int tid = threadIdx.x;
    int wave = tid >> 6, lane = tid & 63;
    int quad = lane >> 4, l15 = lane & 15;
    int qb = blockIdx.x, h = blockIdx.y;
    int kv = h >> 2;                 // H/KV = 4
    int q0 = qb * 64;
    const float scale = 0.08838834764831845f;

    v8s qf[4];
    {
        const u16* qr = &Qb[((size_t)h * TT + q0 + wave * 16 + l15) * HDM];
#pragma unroll
        for (int ks = 0; ks < 4; ++ks) qf[ks] = *(const v8s*)&qr[ks * 32 + quad * 8];
    }

    v4f z4 = {0.f, 0.f, 0.f, 0.f};
    v4f of[8];
#pragma unroll
    for (int i = 0; i < 8; ++i) of[i] = z4;
    float mold[4], lsum[4];
#pragma unroll
    for (int r = 0; r < 4; ++r) { mold[r] = -3.0e38f; lsum[r] = 0.f; }
    u16* Pw = &Pl[wave * 16 * 72];

    for (int s0 = 0; s0 <= q0; s0 += 64) {
        __syncthreads();
#pragma unroll
        for (int c = 0; c < 4; ++c) {
            int ch = wave * 4 + c;
            gl2lds16(&Kb[((size_t)kv * TT + s0 + ch * 4 + (lane >> 4)) * HDM + (lane & 15) * 8],
                     &Kl[ch * 512]);
            gl2lds16(&Vt[((size_t)kv * HDM + ch * 8 + (lane >> 3)) * TT + s0 + (lane & 7) * 8],
                     &Vl[ch * 512]);
        }
        __syncthreads();
        // S = Q @ K^T  (C-layout: row=quad*4+r, col=l15 within n-tile)
        v4f sf[4];
#pragma unroll
        for (int nt = 0; nt < 4; ++nt) {
            v4f cacc = z4;
#pragma unroll
            for (int ks = 0; ks < 4; ++ks)
                cacc = __builtin_amdgcn_mfma_f32_16x16x32_bf16(
                    qf[ks], *(const v8s*)&Kl[(nt * 16 + l15) * 128 + ks * 32 + quad * 8],
                    cacc, 0, 0, 0);
            sf[nt] = cacc;
        }
        float mrow[4];
#pragma unroll
        for (int r = 0; r < 4; ++r) mrow[r] = -3.0e38f;
#pragma unroll
        for (int nt = 0; nt < 4; ++nt) {
            int sg = s0 + nt * 16 + l15;
#pragma unroll
            for (int r = 0; r < 4; ++r) {
                int qg = q0 + wave * 16 + quad * 4 + r;
                float v = sf[nt][r] * scale;
                if (sg > qg) v = -3.0e38f;   // causal mask
                sf[nt][r] = v;
                mrow[r] = fmaxf(mrow[r], v);
            }
        }
#pragma unroll
        for (int off = 1; off < 16; off <<= 1)
#pragma unroll
            for (int r = 0; r < 4; ++r)
                mrow[r] = fmaxf(mrow[r], __shfl_xor(mrow[r], off, 64));
        float alpha[4], lrow[4];
#pragma unroll
        for (int r = 0; r < 4; ++r) {
            float mn = fmaxf(mold[r], mrow[r]);
            alpha[r] = __expf(mold[r] - mn);
            mold[r] = mn;
            lrow[r] = 0.f;
        }
#pragma unroll
        for (int nt = 0; nt < 4; ++nt)
#pragma unroll
            for (int r = 0; r < 4; ++r) {
                float p = __expf(sf[nt][r] - mold[r]);
                sf[nt][r] = p;
                lrow[r] += p;
            }
#pragma unroll
        for (int off = 1; off < 16; off <<= 1)
#pragma unroll
            for (int r = 0; r < 4; ++r) lrow[r] += __shfl_xor(lrow[r], off, 64);
#pragma unroll
        for (int r = 0; r < 4; ++r) lsum[r] = lsum[r] * alpha[r] + lrow[r];
        // P: C-layout -> LDS (A-layout source for PV)
#pragma unroll
        for (int nt = 0; nt < 4; ++nt)
#pragma unroll
            for (int r = 0; r < 4; ++r)
                Pw[(quad * 4 + r) * 72 + nt * 16 + l15] = f2bf(sf[nt][r]);
        // rescale O
#pragma unroll
        for (int i = 0; i < 8; ++i)
#pragma unroll
            for (int r = 0; r < 4; ++r) of[i][r] *= alpha[r];
        // O += P @ V
#pragma unroll
        for (int sub = 0; sub < 2; ++sub) {
            v8s pa = *(const v8s*)&Pw[l15 * 72 + sub * 32 + quad * 8];
#pragma unroll
            for (int nt = 0; nt < 8; ++nt)
                of[nt] = __builtin_amdgcn_mfma_f32_16x16x32_bf16(
                    pa, *(const v8s*)&Vl[(nt * 16 + l15) * 64 + sub * 32 + quad * 8],
                    of[nt], 0, 0, 0);
        }
    }
    float invl[4];
#pragma unroll
    for (int r = 0; r < 4; ++r) invl[r] = 1.0f / lsum[r];
#pragma unroll
    for (int nt = 0; nt < 8; ++nt)
#pragma unroll
        for (int r = 0; r < 4; ++r)
            Ob[(size_t)(q0 + wave * 16 + quad * 4 + r) * (NH * HDM) + h * HDM + nt * 16 + l15] =
                f2bf(of[nt][r] * invl[r]);
}

extern "C" void kernel_launch(void* const* d_in, const int* in_sizes, int n_in,
                              void* d_out, int out_size, void* d_ws, size_t ws_size,
                              hipStream_t stream)
{
    (void)in_sizes; (void)n_in; (void)out_size; (void)ws_size;
    const int*   positions = (const int*)d_in[0];
    const float* hidden    = (const float*)d_in[1];
    const float* w_qkv     = (const float*)d_in[2];
    const float* q_norm_w  = (const float*)d_in[3];
    const float* k_norm_w  = (const float*)d_in[4];
    const float* w_o       = (const float*)d_in[5];
    float* out = (float*)d_out;
    char* ws = (char*)d_ws;
    char* ob = (char*)d_out;

    // ---- d_ws layout (peak = 48 MiB exactly) ----
    u16* hid_bf = (u16*)(ws + 0);                 // [2048][4096] bf16   16 MiB
    u16* Bsl    = (u16*)(ws + (size_t)16777216);  // slice buf, <= 32 MiB
    u16* attnO  = (u16*)(ws + 0);                 // aliases hid_bf (dead after QKV GEMMs)

    // ---- d_out-hosted scratch (25.2 MB + 1 MB <= 33.5 MB; all dead before final GEMM) ----
    u16*   Qb   = (u16*)(ob + 0);                 // [32][2048][128]     16 MiB
    u16*   Kb   = (u16*)(ob + (size_t)16777216);  // [8][2048][128]      4 MiB
    u16*   Vt   = (u16*)(ob + (size_t)20971520);  // [8][128][2048]      4 MiB
    float* cosT = (float*)(ob + (size_t)25165824);// [2048][64]          0.5 MiB
    float* sinT = (float*)(ob + (size_t)25690112);// [2048][64]          0.5 MiB

    cast_bf_kernel<<<4096, 256, 0, stream>>>(hidden, hid_bf);
    rope_tab_kernel<<<512, 256, 0, stream>>>(positions, cosT, sinT);

    // Q columns of w_qkv (cols 0..4095) -> slice, then Q-head GEMM
    transpose_cast_kernel<<<dim3(64, 64), 256, 0, stream>>>(w_qkv, Bsl, 4096, NQKV, 0);
    gemm_bt_kernel<1><<<dim3(32, 16), 256, 0, stream>>>(
        hid_bf, Bsl, nullptr, 4096, 0, q_norm_w, k_norm_w, cosT, sinT, Qb, Kb, Vt);

    // KV columns of w_qkv (cols 4096..6143) -> slice, then K/V-head GEMM
    transpose_cast_kernel<<<dim3(32, 64), 256, 0, stream>>>(w_qkv, Bsl, 4096, NQKV, 4096);
    gemm_bt_kernel<1><<<dim3(16, 16), 256, 0, stream>>>(
        hid_bf, Bsl, nullptr, 4096, 32, q_norm_w, k_norm_w, cosT, sinT, Qb, Kb, Vt);

    // attention: reads Qb/Kb/Vt (d_out), writes attnO (ws, aliases hid_bf)
    attn_kernel<<<dim3(32, 32), 256, 0, stream>>>(Qb, Kb, Vt, attnO);

    // out-proj: w_o -> slice, GEMM writes fp32 result over all of d_out
    transpose_cast_kernel<<<dim3(64, 64), 256, 0, stream>>>(w_o, Bsl, 4096, 4096, 0);
    gemm_bt_kernel<0><<<dim3(32, 16), 256, 0, stream>>>(
        attnO, Bsl, out, 4096, 0, nullptr, nullptr, nullptr, nullptr, nullptr, nullptr, nullptr);
}

// Round 3
// 604.934 us; speedup vs baseline: 1.3079x; 1.3079x over previous
//
#include <hip/hip_runtime.h>

#define TT   2048
#define DD   4096
#define NH   32
#define NKVH 8
#define HDM  128
#define KD   4096
#define NQKV 6144

typedef unsigned short u16;
typedef short v8s __attribute__((ext_vector_type(8)));
typedef float v4f __attribute__((ext_vector_type(4)));

__device__ __forceinline__ u16 f2bf(float f) {
    unsigned u = __builtin_bit_cast(unsigned, f);
    u += 0x7fffu + ((u >> 16) & 1u);   // round-to-nearest-even
    return (u16)(u >> 16);
}
__device__ __forceinline__ float bf2f(u16 h) {
    return __builtin_bit_cast(float, ((unsigned)h) << 16);
}
__device__ __forceinline__ void gl2lds16(const void* g, void* l) {
    // async global->LDS, 16B/lane; LDS dest = wave-uniform base + lane*16
    using gv = const __attribute__((address_space(1))) void;
    using lv = __attribute__((address_space(3))) void;
    __builtin_amdgcn_global_load_lds((gv*)g, (lv*)l, 16, 0, 0);
}

// ---------------- cast hidden fp32 -> bf16 ----------------
__global__ __launch_bounds__(256) void cast_bf_kernel(const float* __restrict__ in,
                                                      u16* __restrict__ out) {
    size_t i = ((size_t)blockIdx.x * 256 + threadIdx.x) * 8;
    float4 a = *(const float4*)&in[i];
    float4 b = *(const float4*)&in[i + 4];
    v8s tv;
    tv[0] = (short)f2bf(a.x); tv[1] = (short)f2bf(a.y);
    tv[2] = (short)f2bf(a.z); tv[3] = (short)f2bf(a.w);
    tv[4] = (short)f2bf(b.x); tv[5] = (short)f2bf(b.y);
    tv[6] = (short)f2bf(b.z); tv[7] = (short)f2bf(b.w);
    *(v8s*)&out[i] = tv;
}

// -------- transpose + cast slice: out[n][k] = bf16(in[k][n_off + n]) --------
__global__ __launch_bounds__(256) void transpose_cast_kernel(const float* __restrict__ in,
                                                             u16* __restrict__ out,
                                                             int K, int N, int n_off) {
    __shared__ float tile[64][65];
    int n0 = blockIdx.x * 64, k0 = blockIdx.y * 64;
    int t = threadIdx.x;
    int rc = t >> 4;
    int cc = (t & 15) * 4;
#pragma unroll
    for (int p = 0; p < 4; ++p) {
        int k = p * 16 + rc;
        float4 v = *(const float4*)&in[(size_t)(k0 + k) * N + n_off + n0 + cc];
        tile[k][cc] = v.x; tile[k][cc + 1] = v.y;
        tile[k][cc + 2] = v.z; tile[k][cc + 3] = v.w;
    }
    __syncthreads();
    int rn = t >> 3;
    int ck = (t & 7) * 8;
#pragma unroll
    for (int p = 0; p < 2; ++p) {
        int n = p * 32 + rn;
        v8s tv;
#pragma unroll
        for (int j = 0; j < 8; ++j) tv[j] = (short)f2bf(tile[ck + j][n]);
        *(v8s*)&out[(size_t)(n0 + n) * K + k0 + ck] = tv;
    }
}

// ---------------- RoPE cos/sin table: [T][64] ----------------
__global__ __launch_bounds__(256) void rope_tab_kernel(const int* __restrict__ positions,
                                                       float* __restrict__ cosT,
                                                       float* __restrict__ sinT) {
    int idx = blockIdx.x * 256 + threadIdx.x;   // T*64 threads
    int tp = idx >> 6, i = idx & 63;
    float invf = exp2f(-(float)i * 0.31143075889569023f);  // log2(1e6)/64
    float f = (float)positions[tp] * invf;
    cosT[idx] = cosf(f);
    sinT[idx] = sinf(f);
}

// ---------------- GEMM: C[M,:] = A[M,K]bf16 @ Bt_slice[N,K]^T bf16 ----------------
// Bt is a column-slice, slice-local rows; nblk_off = global 128-col block offset.
// MODE 0: fp32 C store at global cols.  MODE 1: fused QK-norm + RoPE -> Q/K/Vt
//         (Q additionally pre-scaled by 1/sqrt(HD) so attn skips the scale mult).
template <int MODE>
__global__ __launch_bounds__(256) void gemm_bt_kernel(
    const u16* __restrict__ A, const u16* __restrict__ Bt, float* __restrict__ C, int N,
    int nblk_off,
    const float* __restrict__ qw, const float* __restrict__ kw,
    const float* __restrict__ cosT, const float* __restrict__ sinT,
    u16* __restrict__ Qb, u16* __restrict__ Kb, u16* __restrict__ Vt)
{
    __shared__ __align__(16) u16 smem[16896];   // stage: A[128][64]+B[128][64]; epilogue: Ct[128][132]
    u16* As = smem;
    u16* Bs = smem + 8192;
    int tid = threadIdx.x;
    int wave = tid >> 6, lane = tid & 63;
    int quad = lane >> 4, l15 = lane & 15;
    int wm = wave >> 1, wn = wave & 1;
    int m0 = blockIdx.y * 128, n0 = blockIdx.x * 128;   // n0 is slice-local

    v4f acc[4][4];
    v4f z4 = {0.f, 0.f, 0.f, 0.f};
#pragma unroll
    for (int mi = 0; mi < 4; ++mi)
#pragma unroll
        for (int ni = 0; ni < 4; ++ni) acc[mi][ni] = z4;

    int srow = lane >> 3;
    int scol = (lane & 7) * 8;
    const u16* Ag = &A[(size_t)m0 * KD + scol];
    const u16* Bg = &Bt[(size_t)n0 * KD + scol];

    for (int k0 = 0; k0 < KD; k0 += 64) {
        __syncthreads();
#pragma unroll
        for (int c = 0; c < 4; ++c) {
            int ch = wave * 4 + c;
            int row = ch * 8 + srow;
            gl2lds16(&Ag[(size_t)row * KD + k0], &As[ch * 512]);
            gl2lds16(&Bg[(size_t)row * KD + k0], &Bs[ch * 512]);
        }
        __syncthreads();
#pragma unroll
        for (int ks = 0; ks < 2; ++ks) {
            v8s af[4], bfr[4];
#pragma unroll
            for (int mi = 0; mi < 4; ++mi)
                af[mi] = *(const v8s*)&As[(wm * 64 + mi * 16 + l15) * 64 + ks * 32 + quad * 8];
#pragma unroll
            for (int ni = 0; ni < 4; ++ni)
                bfr[ni] = *(const v8s*)&Bs[(wn * 64 + ni * 16 + l15) * 64 + ks * 32 + quad * 8];
#pragma unroll
            for (int mi = 0; mi < 4; ++mi)
#pragma unroll
                for (int ni = 0; ni < 4; ++ni)
                    acc[mi][ni] = __builtin_amdgcn_mfma_f32_16x16x32_bf16(
                        af[mi], bfr[ni], acc[mi][ni], 0, 0, 0);
        }
    }

    if (MODE == 0) {
        int ng0 = (nblk_off + blockIdx.x) * 128;
#pragma unroll
        for (int mi = 0; mi < 4; ++mi)
#pragma unroll
            for (int ni = 0; ni < 4; ++ni)
#pragma unroll
                for (int r = 0; r < 4; ++r)
                    C[(size_t)(m0 + wm * 64 + mi * 16 + quad * 4 + r) * N +
                      (ng0 + wn * 64 + ni * 16 + l15)] = acc[mi][ni][r];
    } else {
        // ---- fused epilogue: this block's 128 cols == one head ----
        __syncthreads();
        u16* Ct = smem;   // [128][132] bf16, padded stride
#pragma unroll
        for (int mi = 0; mi < 4; ++mi)
#pragma unroll
            for (int ni = 0; ni < 4; ++ni)
#pragma unroll
                for (int r = 0; r < 4; ++r)
                    Ct[(wm * 64 + mi * 16 + quad * 4 + r) * 132 + wn * 64 + ni * 16 + l15] =
                        f2bf(acc[mi][ni][r]);
        __syncthreads();
        int head = nblk_off + blockIdx.x;    // 0..31 q, 32..39 k, 40..47 v
        int t0 = blockIdx.y * 128;
        if (head < 40) {
            if (tid < 128) {
                int row = tid;
                const float* w = (head < 32) ? qw : kw;
                float ss = 0.f;
                for (int i = 0; i < 128; ++i) {
                    float x = bf2f(Ct[row * 132 + i]);
                    ss += x * x;
                }
                float rs = rsqrtf(ss * (1.0f / 128.0f) + 1e-6f);
                if (head < 32) rs *= 0.08838834764831845f;   // fold 1/sqrt(HD) into Q
                int ti = t0 + row;
                for (int i = 0; i < 64; ++i) {
                    float x1 = bf2f(Ct[row * 132 + i]) * rs * w[i];
                    float x2 = bf2f(Ct[row * 132 + 64 + i]) * rs * w[64 + i];
                    float c = cosT[ti * 64 + i], s = sinT[ti * 64 + i];
                    Ct[row * 132 + i]      = f2bf(x1 * c - x2 * s);
                    Ct[row * 132 + 64 + i] = f2bf(x2 * c + x1 * s);
                }
            }
            __syncthreads();
            u16* dst = (head < 32) ? &Qb[((size_t)head * TT + t0) * HDM]
                                   : &Kb[((size_t)(head - 32) * TT + t0) * HDM];
            for (int cix = tid; cix < 128 * 16; cix += 256) {
                int row = cix >> 4, part = (cix & 15) * 8;
                v8s tv;
#pragma unroll
                for (int j = 0; j < 8; ++j) tv[j] = (short)Ct[row * 132 + part + j];
                *(v8s*)&dst[row * HDM + part] = tv;
            }
        } else {
            // V head: write transposed Vt[kv][hd][t]
            int kvh = head - 40;
            if (tid < 128) {
                int hd = tid;
#pragma unroll
                for (int tb = 0; tb < 16; ++tb) {
                    v8s tv;
#pragma unroll
                    for (int j = 0; j < 8; ++j) tv[j] = (short)Ct[(tb * 8 + j) * 132 + hd];
                    *(v8s*)&Vt[((size_t)kvh * HDM + hd) * TT + t0 + tb * 8] = tv;
                }
            }
        }
    }
}

// ---------------- flash attention (causal, GQA) ----------------
// 1D grid 1024, longest-first: qb = 31 - (idx>>5), h = idx&31.
// LDS layouts XOR-swizzled (phys 16B-chunk = logical ^ (row&7)) to kill
// the 16-way bank conflicts of power-of-2 row strides; gl2lds16 staging
// permutes the GLOBAL source address per lane (LDS dest must stay lane*16).
__global__ __launch_bounds__(256) void attn_kernel(
    const u16* __restrict__ Qb, const u16* __restrict__ Kb,
    const u16* __restrict__ Vt, u16* __restrict__ Ob)
{
    __shared__ __align__(16) u16 Kl[64 * 128];   // [s][hd] swizzled, 16 chunks/row
    __shared__ __align__(16) u16 Vl[128 * 64];   // [hd][s] swizzled, 8 chunks/row
    __shared__ __align__(16) u16 Pl[4 * 16 * 64];  // per-wave P, swizzled, 8 chunks/row
    int tid = threadIdx.x;
    int wave = tid >> 6, lane = tid & 63;
    int quad = lane >> 4, l15 = lane & 15;
    int idx = blockIdx.x;
    int h = idx & 31;
    int qb = 31 - (idx >> 5);        // longest blocks dispatch first
    int kv = h >> 2;                 // H/KV = 4
    int q0 = qb * 64;
    int lm = l15 & 7;                // swizzle mask for this lane's row group

    v8s qf[4];
    {
        const u16* qr = &Qb[((size_t)h * TT + q0 + wave * 16 + l15) * HDM];
#pragma unroll
        for (int ks = 0; ks < 4; ++ks) qf[ks] = *(const v8s*)&qr[ks * 32 + quad * 8];
    }

    v4f z4 = {0.f, 0.f, 0.f, 0.f};
    v4f of[8];
#pragma unroll
    for (int i = 0; i < 8; ++i) of[i] = z4;
    float mold[4], lsum[4];
#pragma unroll
    for (int r = 0; r < 4; ++r) { mold[r] = -3.0e38f; lsum[r] = 0.f; }
    u16* Pw = &Pl[wave * 1024];

    for (int s0 = 0; s0 <= q0; s0 += 64) {
        __syncthreads();
#pragma unroll
        for (int c = 0; c < 4; ++c) {
            int ch = wave * 4 + c;
            int rk = ch * 4 + (lane >> 4);              // Kl row (s-local)
            int ck = (lane & 15) ^ (rk & 7);            // logical chunk to fetch
            gl2lds16(&Kb[((size_t)kv * TT + s0 + rk) * HDM + ck * 8], &Kl[ch * 512]);
            int rv = ch * 8 + (lane >> 3);              // Vl row (hd)
            int cv = (lane & 7) ^ (rv & 7);
            gl2lds16(&Vt[((size_t)kv * HDM + rv) * TT + s0 + cv * 8], &Vl[ch * 512]);
        }
        __syncthreads();
        // S = Q @ K^T  (C-layout: row=quad*4+r, col=l15 within n-tile)
        v4f sf[4];
#pragma unroll
        for (int nt = 0; nt < 4; ++nt) {
            v4f cacc = z4;
#pragma unroll
            for (int ks = 0; ks < 4; ++ks)
                cacc = __builtin_amdgcn_mfma_f32_16x16x32_bf16(
                    qf[ks],
                    *(const v8s*)&Kl[(nt * 16 + l15) * 128 + (((ks * 4 + quad) ^ lm) << 3)],
                    cacc, 0, 0, 0);
            sf[nt] = cacc;
        }
        if (s0 == q0) {   // only the diagonal tile needs the causal mask
#pragma unroll
            for (int nt = 0; nt < 4; ++nt) {
                int sg = s0 + nt * 16 + l15;
#pragma unroll
                for (int r = 0; r < 4; ++r) {
                    int qg = q0 + wave * 16 + quad * 4 + r;
                    if (sg > qg) sf[nt][r] = -3.0e38f;
                }
            }
        }
        float mrow[4];
#pragma unroll
        for (int r = 0; r < 4; ++r) mrow[r] = -3.0e38f;
#pragma unroll
        for (int nt = 0; nt < 4; ++nt)
#pragma unroll
            for (int r = 0; r < 4; ++r) mrow[r] = fmaxf(mrow[r], sf[nt][r]);
#pragma unroll
        for (int off = 1; off < 16; off <<= 1)
#pragma unroll
            for (int r = 0; r < 4; ++r)
                mrow[r] = fmaxf(mrow[r], __shfl_xor(mrow[r], off, 64));
        float alpha[4], lrow[4];
#pragma unroll
        for (int r = 0; r < 4; ++r) {
            float mn = fmaxf(mold[r], mrow[r]);
            alpha[r] = __expf(mold[r] - mn);
            mold[r] = mn;
            lrow[r] = 0.f;
        }
#pragma unroll
        for (int nt = 0; nt < 4; ++nt)
#pragma unroll
            for (int r = 0; r < 4; ++r) {
                float p = __expf(sf[nt][r] - mold[r]);
                sf[nt][r] = p;
                lrow[r] += p;
            }
#pragma unroll
        for (int off = 1; off < 16; off <<= 1)
#pragma unroll
            for (int r = 0; r < 4; ++r) lrow[r] += __shfl_xor(lrow[r], off, 64);
#pragma unroll
        for (int r = 0; r < 4; ++r) lsum[r] = lsum[r] * alpha[r] + lrow[r];
        // P: C-layout -> swizzled LDS (A-layout source for PV)
#pragma unroll
        for (int nt = 0; nt < 4; ++nt)
#pragma unroll
            for (int r = 0; r < 4; ++r) {
                int row = quad * 4 + r;
                int pch = ((nt << 1) + (l15 >> 3)) ^ (row & 7);
                Pw[row * 64 + pch * 8 + (l15 & 7)] = f2bf(sf[nt][r]);
            }
        // rescale O
#pragma unroll
        for (int i = 0; i < 8; ++i)
#pragma unroll
            for (int r = 0; r < 4; ++r) of[i][r] *= alpha[r];
        // O += P @ V
#pragma unroll
        for (int sub = 0; sub < 2; ++sub) {
            v8s pa = *(const v8s*)&Pw[l15 * 64 + ((((sub << 2) + quad) ^ lm) << 3)];
#pragma unroll
            for (int nt = 0; nt < 8; ++nt)
                of[nt] = __builtin_amdgcn_mfma_f32_16x16x32_bf16(
                    pa,
                    *(const v8s*)&Vl[(nt * 16 + l15) * 64 + ((((sub << 2) + quad) ^ lm) << 3)],
                    of[nt], 0, 0, 0);
        }
    }
    float invl[4];
#pragma unroll
    for (int r = 0; r < 4; ++r) invl[r] = 1.0f / lsum[r];
#pragma unroll
    for (int nt = 0; nt < 8; ++nt)
#pragma unroll
        for (int r = 0; r < 4; ++r)
            Ob[(size_t)(q0 + wave * 16 + quad * 4 + r) * (NH * HDM) + h * HDM + nt * 16 + l15] =
                f2bf(of[nt][r] * invl[r]);
}

extern "C" void kernel_launch(void* const* d_in, const int* in_sizes, int n_in,
                              void* d_out, int out_size, void* d_ws, size_t ws_size,
                              hipStream_t stream)
{
    (void)in_sizes; (void)n_in; (void)out_size; (void)ws_size;
    const int*   positions = (const int*)d_in[0];
    const float* hidden    = (const float*)d_in[1];
    const float* w_qkv     = (const float*)d_in[2];
    const float* q_norm_w  = (const float*)d_in[3];
    const float* k_norm_w  = (const float*)d_in[4];
    const float* w_o       = (const float*)d_in[5];
    float* out = (float*)d_out;
    char* ws = (char*)d_ws;
    char* ob = (char*)d_out;

    // ---- d_ws layout (peak = 48 MiB exactly) ----
    u16* hid_bf = (u16*)(ws + 0);                 // [2048][4096] bf16   16 MiB
    u16* Bsl    = (u16*)(ws + (size_t)16777216);  // slice buf, <= 32 MiB
    u16* attnO  = (u16*)(ws + 0);                 // aliases hid_bf (dead after QKV GEMMs)

    // ---- d_out-hosted scratch (25.2 MB + 1 MB <= 33.5 MB; all dead before final GEMM) ----
    u16*   Qb   = (u16*)(ob + 0);                 // [32][2048][128]     16 MiB
    u16*   Kb   = (u16*)(ob + (size_t)16777216);  // [8][2048][128]      4 MiB
    u16*   Vt   = (u16*)(ob + (size_t)20971520);  // [8][128][2048]      4 MiB
    float* cosT = (float*)(ob + (size_t)25165824);// [2048][64]          0.5 MiB
    float* sinT = (float*)(ob + (size_t)25690112);// [2048][64]          0.5 MiB

    cast_bf_kernel<<<4096, 256, 0, stream>>>(hidden, hid_bf);
    rope_tab_kernel<<<512, 256, 0, stream>>>(positions, cosT, sinT);

    // Q columns of w_qkv (cols 0..4095) -> slice, then Q-head GEMM
    transpose_cast_kernel<<<dim3(64, 64), 256, 0, stream>>>(w_qkv, Bsl, 4096, NQKV, 0);
    gemm_bt_kernel<1><<<dim3(32, 16), 256, 0, stream>>>(
        hid_bf, Bsl, nullptr, 4096, 0, q_norm_w, k_norm_w, cosT, sinT, Qb, Kb, Vt);

    // KV columns of w_qkv (cols 4096..6143) -> slice, then K/V-head GEMM
    transpose_cast_kernel<<<dim3(32, 64), 256, 0, stream>>>(w_qkv, Bsl, 4096, NQKV, 4096);
    gemm_bt_kernel<1><<<dim3(16, 16), 256, 0, stream>>>(
        hid_bf, Bsl, nullptr, 4096, 32, q_norm_w, k_norm_w, cosT, sinT, Qb, Kb, Vt);

    // attention: reads Qb/Kb/Vt (d_out), writes attnO (ws, aliases hid_bf)
    attn_kernel<<<dim3(1024), 256, 0, stream>>>(Qb, Kb, Vt, attnO);

    // out-proj: w_o -> slice, GEMM writes fp32 result over all of d_out
    transpose_cast_kernel<<<dim3(64, 64), 256, 0, stream>>>(w_o, Bsl, 4096, 4096, 0);
    gemm_bt_kernel<0><<<dim3(32, 16), 256, 0, stream>>>(
        attnO, Bsl, out, 4096, 0, nullptr, nullptr, nullptr, nullptr, nullptr, nullptr, nullptr);
}

// Round 4
// 601.748 us; speedup vs baseline: 1.3148x; 1.0053x over previous
//
#include <hip/hip_runtime.h>

#define TT   2048
#define DD   4096
#define NH   32
#define NKVH 8
#define HDM  128
#define KD   4096
#define NQKV 6144

typedef unsigned short u16;
typedef short v8s __attribute__((ext_vector_type(8)));
typedef float v4f __attribute__((ext_vector_type(4)));

__device__ __forceinline__ u16 f2bf(float f) {
    unsigned u = __builtin_bit_cast(unsigned, f);
    u += 0x7fffu + ((u >> 16) & 1u);   // round-to-nearest-even
    return (u16)(u >> 16);
}
__device__ __forceinline__ float bf2f(u16 h) {
    return __builtin_bit_cast(float, ((unsigned)h) << 16);
}
__device__ __forceinline__ void gl2lds16(const void* g, void* l) {
    // async global->LDS, 16B/lane; LDS dest = wave-uniform base + lane*16
    using gv = const __attribute__((address_space(1))) void;
    using lv = __attribute__((address_space(3))) void;
    __builtin_amdgcn_global_load_lds((gv*)g, (lv*)l, 16, 0, 0);
}

// ------- prep: cast hidden fp32->bf16 (blocks 0..4095) + RoPE table (4096..4607) -------
__global__ __launch_bounds__(256) void prep_kernel(const float* __restrict__ in,
                                                   u16* __restrict__ out,
                                                   const int* __restrict__ positions,
                                                   float* __restrict__ cosT,
                                                   float* __restrict__ sinT) {
    int b = blockIdx.x;
    if (b < 4096) {
        size_t i = ((size_t)b * 256 + threadIdx.x) * 8;
        float4 a = *(const float4*)&in[i];
        float4 c = *(const float4*)&in[i + 4];
        v8s tv;
        tv[0] = (short)f2bf(a.x); tv[1] = (short)f2bf(a.y);
        tv[2] = (short)f2bf(a.z); tv[3] = (short)f2bf(a.w);
        tv[4] = (short)f2bf(c.x); tv[5] = (short)f2bf(c.y);
        tv[6] = (short)f2bf(c.z); tv[7] = (short)f2bf(c.w);
        *(v8s*)&out[i] = tv;
    } else {
        int idx = (b - 4096) * 256 + threadIdx.x;   // T*64 entries
        int tp = idx >> 6, i = idx & 63;
        float invf = exp2f(-(float)i * 0.31143075889569023f);  // log2(1e6)/64
        float f = (float)positions[tp] * invf;
        cosT[idx] = cosf(f);
        sinT[idx] = sinf(f);
    }
}

// -------- transpose + cast: out[n][k] = bf16(in[k][n]) --------
__global__ __launch_bounds__(256) void transpose_cast_kernel(const float* __restrict__ in,
                                                             u16* __restrict__ out,
                                                             int K, int N) {
    __shared__ float tile[64][65];
    int n0 = blockIdx.x * 64, k0 = blockIdx.y * 64;
    int t = threadIdx.x;
    int rc = t >> 4;
    int cc = (t & 15) * 4;
#pragma unroll
    for (int p = 0; p < 4; ++p) {
        int k = p * 16 + rc;
        float4 v = *(const float4*)&in[(size_t)(k0 + k) * N + n0 + cc];
        tile[k][cc] = v.x; tile[k][cc + 1] = v.y;
        tile[k][cc + 2] = v.z; tile[k][cc + 3] = v.w;
    }
    __syncthreads();
    int rn = t >> 3;
    int ck = (t & 7) * 8;
#pragma unroll
    for (int p = 0; p < 2; ++p) {
        int n = p * 32 + rn;
        v8s tv;
#pragma unroll
        for (int j = 0; j < 8; ++j) tv[j] = (short)f2bf(tile[ck + j][n]);
        *(v8s*)&out[(size_t)(n0 + n) * K + k0 + ck] = tv;
    }
}

// ---------------- GEMM: C[M,:] = A[M,K]bf16 @ Bt[N,K]^T bf16 ----------------
// MODE 0: fp32 C store.  MODE 1: fused QK-norm + RoPE -> Q/K/Vt
//         (Q additionally pre-scaled by 1/sqrt(HD) so attn skips the scale mult).
template <int MODE>
__global__ __launch_bounds__(256) void gemm_bt_kernel(
    const u16* __restrict__ A, const u16* __restrict__ Bt, float* __restrict__ C, int N,
    const float* __restrict__ qw, const float* __restrict__ kw,
    const float* __restrict__ cosT, const float* __restrict__ sinT,
    u16* __restrict__ Qb, u16* __restrict__ Kb, u16* __restrict__ Vt)
{
    __shared__ __align__(16) u16 smem[16896];   // stage: A[128][64]+B[128][64]; epilogue: Ct[128][132]
    u16* As = smem;
    u16* Bs = smem + 8192;
    int tid = threadIdx.x;
    int wave = tid >> 6, lane = tid & 63;
    int quad = lane >> 4, l15 = lane & 15;
    int wm = wave >> 1, wn = wave & 1;
    int m0 = blockIdx.y * 128, n0 = blockIdx.x * 128;

    v4f acc[4][4];
    v4f z4 = {0.f, 0.f, 0.f, 0.f};
#pragma unroll
    for (int mi = 0; mi < 4; ++mi)
#pragma unroll
        for (int ni = 0; ni < 4; ++ni) acc[mi][ni] = z4;

    int srow = lane >> 3;
    int scol = (lane & 7) * 8;
    const u16* Ag = &A[(size_t)m0 * KD + scol];
    const u16* Bg = &Bt[(size_t)n0 * KD + scol];

    for (int k0 = 0; k0 < KD; k0 += 64) {
        __syncthreads();
#pragma unroll
        for (int c = 0; c < 4; ++c) {
            int ch = wave * 4 + c;
            int row = ch * 8 + srow;
            gl2lds16(&Ag[(size_t)row * KD + k0], &As[ch * 512]);
            gl2lds16(&Bg[(size_t)row * KD + k0], &Bs[ch * 512]);
        }
        __syncthreads();
#pragma unroll
        for (int ks = 0; ks < 2; ++ks) {
            v8s af[4], bfr[4];
#pragma unroll
            for (int mi = 0; mi < 4; ++mi)
                af[mi] = *(const v8s*)&As[(wm * 64 + mi * 16 + l15) * 64 + ks * 32 + quad * 8];
#pragma unroll
            for (int ni = 0; ni < 4; ++ni)
                bfr[ni] = *(const v8s*)&Bs[(wn * 64 + ni * 16 + l15) * 64 + ks * 32 + quad * 8];
#pragma unroll
            for (int mi = 0; mi < 4; ++mi)
#pragma unroll
                for (int ni = 0; ni < 4; ++ni)
                    acc[mi][ni] = __builtin_amdgcn_mfma_f32_16x16x32_bf16(
                        af[mi], bfr[ni], acc[mi][ni], 0, 0, 0);
        }
    }

    if (MODE == 0) {
#pragma unroll
        for (int mi = 0; mi < 4; ++mi)
#pragma unroll
            for (int ni = 0; ni < 4; ++ni)
#pragma unroll
                for (int r = 0; r < 4; ++r)
                    C[(size_t)(m0 + wm * 64 + mi * 16 + quad * 4 + r) * N +
                      (n0 + wn * 64 + ni * 16 + l15)] = acc[mi][ni][r];
    } else {
        // ---- fused epilogue: this block's 128 cols == one head ----
        __syncthreads();
        u16* Ct = smem;   // [128][132] bf16, padded stride
#pragma unroll
        for (int mi = 0; mi < 4; ++mi)
#pragma unroll
            for (int ni = 0; ni < 4; ++ni)
#pragma unroll
                for (int r = 0; r < 4; ++r)
                    Ct[(wm * 64 + mi * 16 + quad * 4 + r) * 132 + wn * 64 + ni * 16 + l15] =
                        f2bf(acc[mi][ni][r]);
        __syncthreads();
        int head = blockIdx.x;    // 0..31 q, 32..39 k, 40..47 v
        int t0 = blockIdx.y * 128;
        if (head < 40) {
            if (tid < 128) {
                int row = tid;
                const float* w = (head < 32) ? qw : kw;
                float ss = 0.f;
                for (int i = 0; i < 128; ++i) {
                    float x = bf2f(Ct[row * 132 + i]);
                    ss += x * x;
                }
                float rs = rsqrtf(ss * (1.0f / 128.0f) + 1e-6f);
                if (head < 32) rs *= 0.08838834764831845f;   // fold 1/sqrt(HD) into Q
                int ti = t0 + row;
                for (int i = 0; i < 64; ++i) {
                    float x1 = bf2f(Ct[row * 132 + i]) * rs * w[i];
                    float x2 = bf2f(Ct[row * 132 + 64 + i]) * rs * w[64 + i];
                    float c = cosT[ti * 64 + i], s = sinT[ti * 64 + i];
                    Ct[row * 132 + i]      = f2bf(x1 * c - x2 * s);
                    Ct[row * 132 + 64 + i] = f2bf(x2 * c + x1 * s);
                }
            }
            __syncthreads();
            u16* dst = (head < 32) ? &Qb[((size_t)head * TT + t0) * HDM]
                                   : &Kb[((size_t)(head - 32) * TT + t0) * HDM];
            for (int cix = tid; cix < 128 * 16; cix += 256) {
                int row = cix >> 4, part = (cix & 15) * 8;
                v8s tv;
#pragma unroll
                for (int j = 0; j < 8; ++j) tv[j] = (short)Ct[row * 132 + part + j];
                *(v8s*)&dst[row * HDM + part] = tv;
            }
        } else {
            // V head: write transposed Vt[kv][hd][t]
            int kvh = head - 40;
            if (tid < 128) {
                int hd = tid;
#pragma unroll
                for (int tb = 0; tb < 16; ++tb) {
                    v8s tv;
#pragma unroll
                    for (int j = 0; j < 8; ++j) tv[j] = (short)Ct[(tb * 8 + j) * 132 + hd];
                    *(v8s*)&Vt[((size_t)kvh * HDM + hd) * TT + t0 + tb * 8] = tv;
                }
            }
        }
    }
}

// ---------------- flash attention (causal, GQA) ----------------
// 1D grid 1024, longest-first: qb = 31 - (idx>>5), h = idx&31.
// LDS layouts XOR-swizzled (phys 16B-chunk = logical ^ (row&7)) to kill
// the 16-way bank conflicts of power-of-2 row strides; gl2lds16 staging
// permutes the GLOBAL source address per lane (LDS dest must stay lane*16).
__global__ __launch_bounds__(256) void attn_kernel(
    const u16* __restrict__ Qb, const u16* __restrict__ Kb,
    const u16* __restrict__ Vt, u16* __restrict__ Ob)
{
    __shared__ __align__(16) u16 Kl[64 * 128];   // [s][hd] swizzled, 16 chunks/row
    __shared__ __align__(16) u16 Vl[128 * 64];   // [hd][s] swizzled, 8 chunks/row
    __shared__ __align__(16) u16 Pl[4 * 16 * 64];  // per-wave P, swizzled, 8 chunks/row
    int tid = threadIdx.x;
    int wave = tid >> 6, lane = tid & 63;
    int quad = lane >> 4, l15 = lane & 15;
    int idx = blockIdx.x;
    int h = idx & 31;
    int qb = 31 - (idx >> 5);        // longest blocks dispatch first
    int kv = h >> 2;                 // H/KV = 4
    int q0 = qb * 64;
    int lm = l15 & 7;                // swizzle mask for this lane's row group

    v8s qf[4];
    {
        const u16* qr = &Qb[((size_t)h * TT + q0 + wave * 16 + l15) * HDM];
#pragma unroll
        for (int ks = 0; ks < 4; ++ks) qf[ks] = *(const v8s*)&qr[ks * 32 + quad * 8];
    }

    v4f z4 = {0.f, 0.f, 0.f, 0.f};
    v4f of[8];
#pragma unroll
    for (int i = 0; i < 8; ++i) of[i] = z4;
    float mold[4], lsum[4];
#pragma unroll
    for (int r = 0; r < 4; ++r) { mold[r] = -3.0e38f; lsum[r] = 0.f; }
    u16* Pw = &Pl[wave * 1024];

    for (int s0 = 0; s0 <= q0; s0 += 64) {
        __syncthreads();
#pragma unroll
        for (int c = 0; c < 4; ++c) {
            int ch = wave * 4 + c;
            int rk = ch * 4 + (lane >> 4);              // Kl row (s-local)
            int ck = (lane & 15) ^ (rk & 7);            // logical chunk to fetch
            gl2lds16(&Kb[((size_t)kv * TT + s0 + rk) * HDM + ck * 8], &Kl[ch * 512]);
            int rv = ch * 8 + (lane >> 3);              // Vl row (hd)
            int cv = (lane & 7) ^ (rv & 7);
            gl2lds16(&Vt[((size_t)kv * HDM + rv) * TT + s0 + cv * 8], &Vl[ch * 512]);
        }
        __syncthreads();
        // S = Q @ K^T  (C-layout: row=quad*4+r, col=l15 within n-tile)
        v4f sf[4];
#pragma unroll
        for (int nt = 0; nt < 4; ++nt) {
            v4f cacc = z4;
#pragma unroll
            for (int ks = 0; ks < 4; ++ks)
                cacc = __builtin_amdgcn_mfma_f32_16x16x32_bf16(
                    qf[ks],
                    *(const v8s*)&Kl[(nt * 16 + l15) * 128 + (((ks * 4 + quad) ^ lm) << 3)],
                    cacc, 0, 0, 0);
            sf[nt] = cacc;
        }
        if (s0 == q0) {   // only the diagonal tile needs the causal mask
#pragma unroll
            for (int nt = 0; nt < 4; ++nt) {
                int sg = s0 + nt * 16 + l15;
#pragma unroll
                for (int r = 0; r < 4; ++r) {
                    int qg = q0 + wave * 16 + quad * 4 + r;
                    if (sg > qg) sf[nt][r] = -3.0e38f;
                }
            }
        }
        float mrow[4];
#pragma unroll
        for (int r = 0; r < 4; ++r) mrow[r] = -3.0e38f;
#pragma unroll
        for (int nt = 0; nt < 4; ++nt)
#pragma unroll
            for (int r = 0; r < 4; ++r) mrow[r] = fmaxf(mrow[r], sf[nt][r]);
#pragma unroll
        for (int off = 1; off < 16; off <<= 1)
#pragma unroll
            for (int r = 0; r < 4; ++r)
                mrow[r] = fmaxf(mrow[r], __shfl_xor(mrow[r], off, 64));
        float alpha[4], lrow[4];
#pragma unroll
        for (int r = 0; r < 4; ++r) {
            float mn = fmaxf(mold[r], mrow[r]);
            alpha[r] = __expf(mold[r] - mn);
            mold[r] = mn;
            lrow[r] = 0.f;
        }
#pragma unroll
        for (int nt = 0; nt < 4; ++nt)
#pragma unroll
            for (int r = 0; r < 4; ++r) {
                float p = __expf(sf[nt][r] - mold[r]);
                sf[nt][r] = p;
                lrow[r] += p;
            }
#pragma unroll
        for (int off = 1; off < 16; off <<= 1)
#pragma unroll
            for (int r = 0; r < 4; ++r) lrow[r] += __shfl_xor(lrow[r], off, 64);
#pragma unroll
        for (int r = 0; r < 4; ++r) lsum[r] = lsum[r] * alpha[r] + lrow[r];
        // P: C-layout -> swizzled LDS (A-layout source for PV)
#pragma unroll
        for (int nt = 0; nt < 4; ++nt)
#pragma unroll
            for (int r = 0; r < 4; ++r) {
                int row = quad * 4 + r;
                int pch = ((nt << 1) + (l15 >> 3)) ^ (row & 7);
                Pw[row * 64 + pch * 8 + (l15 & 7)] = f2bf(sf[nt][r]);
            }
        // rescale O
#pragma unroll
        for (int i = 0; i < 8; ++i)
#pragma unroll
            for (int r = 0; r < 4; ++r) of[i][r] *= alpha[r];
        // O += P @ V
#pragma unroll
        for (int sub = 0; sub < 2; ++sub) {
            v8s pa = *(const v8s*)&Pw[l15 * 64 + ((((sub << 2) + quad) ^ lm) << 3)];
#pragma unroll
            for (int nt = 0; nt < 8; ++nt)
                of[nt] = __builtin_amdgcn_mfma_f32_16x16x32_bf16(
                    pa,
                    *(const v8s*)&Vl[(nt * 16 + l15) * 64 + ((((sub << 2) + quad) ^ lm) << 3)],
                    of[nt], 0, 0, 0);
        }
    }
    float invl[4];
#pragma unroll
    for (int r = 0; r < 4; ++r) invl[r] = 1.0f / lsum[r];
#pragma unroll
    for (int nt = 0; nt < 8; ++nt)
#pragma unroll
        for (int r = 0; r < 4; ++r)
            Ob[(size_t)(q0 + wave * 16 + quad * 4 + r) * (NH * HDM) + h * HDM + nt * 16 + l15] =
                f2bf(of[nt][r] * invl[r]);
}

extern "C" void kernel_launch(void* const* d_in, const int* in_sizes, int n_in,
                              void* d_out, int out_size, void* d_ws, size_t ws_size,
                              hipStream_t stream)
{
    (void)in_sizes; (void)n_in; (void)out_size; (void)ws_size;
    const int*   positions = (const int*)d_in[0];
    const float* hidden    = (const float*)d_in[1];
    const float* w_qkv     = (const float*)d_in[2];
    const float* q_norm_w  = (const float*)d_in[3];
    const float* k_norm_w  = (const float*)d_in[4];
    const float* w_o       = (const float*)d_in[5];
    float* out = (float*)d_out;
    char* ws = (char*)d_ws;
    char* ob = (char*)d_out;

    // ---- d_ws layout (peak = 64 MiB exactly) ----
    u16* hid_bf = (u16*)(ws + 0);                 // [2048][4096] bf16      16 MiB
    u16* attnO  = (u16*)(ws + 0);                 // aliases hid_bf (dead after QKV GEMM)
    u16* wqkv_t = (u16*)(ws + (size_t)16777216);  // [6144][4096] bf16      50.33 MiB (ends at 64 MiB)
    u16* wo_t   = (u16*)(ws + (size_t)16777216);  // [4096][4096] bf16, overwrites wqkv_t after QKV GEMM

    // ---- d_out-hosted scratch (26.2 MiB <= 32 MiB; all dead before final GEMM) ----
    u16*   Qb   = (u16*)(ob + 0);                 // [32][2048][128]     16 MiB
    u16*   Kb   = (u16*)(ob + (size_t)16777216);  // [8][2048][128]      4 MiB
    u16*   Vt   = (u16*)(ob + (size_t)20971520);  // [8][128][2048]      4 MiB
    float* cosT = (float*)(ob + (size_t)25165824);// [2048][64]          0.5 MiB
    float* sinT = (float*)(ob + (size_t)25690112);// [2048][64]          0.5 MiB

    // cast hidden -> bf16 + build RoPE tables (one launch)
    prep_kernel<<<4608, 256, 0, stream>>>(hidden, hid_bf, positions, cosT, sinT);

    // full w_qkv transpose+cast, then single fused QKV GEMM (768 blocks = 3/CU)
    transpose_cast_kernel<<<dim3(96, 64), 256, 0, stream>>>(w_qkv, wqkv_t, 4096, NQKV);
    gemm_bt_kernel<1><<<dim3(48, 16), 256, 0, stream>>>(
        hid_bf, wqkv_t, nullptr, NQKV, q_norm_w, k_norm_w, cosT, sinT, Qb, Kb, Vt);

    // attention: reads Qb/Kb/Vt (d_out), writes attnO (ws, aliases hid_bf)
    attn_kernel<<<dim3(1024), 256, 0, stream>>>(Qb, Kb, Vt, attnO);

    // out-proj: w_o -> wo_t (reuses wqkv_t region), GEMM writes fp32 over all of d_out
    transpose_cast_kernel<<<dim3(64, 64), 256, 0, stream>>>(w_o, wo_t, 4096, 4096);
    gemm_bt_kernel<0><<<dim3(32, 16), 256, 0, stream>>>(
        attnO, wo_t, out, 4096, nullptr, nullptr, nullptr, nullptr, nullptr, nullptr, nullptr);
}

// Round 5
// 511.866 us; speedup vs baseline: 1.5457x; 1.1756x over previous
//
#include <hip/hip_runtime.h>

#define TT   2048
#define DD   4096
#define NH   32
#define NKVH 8
#define HDM  128
#define KD   4096
#define NQKV 6144

typedef unsigned short u16;
typedef short v8s __attribute__((ext_vector_type(8)));
typedef float v4f __attribute__((ext_vector_type(4)));

__device__ __forceinline__ u16 f2bf(float f) {
    unsigned u = __builtin_bit_cast(unsigned, f);
    u += 0x7fffu + ((u >> 16) & 1u);   // round-to-nearest-even
    return (u16)(u >> 16);
}
__device__ __forceinline__ float bf2f(u16 h) {
    return __builtin_bit_cast(float, ((unsigned)h) << 16);
}
__device__ __forceinline__ void gl2lds16(const void* g, void* l) {
    // async global->LDS, 16B/lane; LDS dest = wave-uniform base + lane*16
    using gv = const __attribute__((address_space(1))) void;
    using lv = __attribute__((address_space(3))) void;
    __builtin_amdgcn_global_load_lds((gv*)g, (lv*)l, 16, 0, 0);
}

// ------- prep: cast hidden fp32->bf16 (blocks 0..4095) + RoPE table (4096..4607) -------
__global__ __launch_bounds__(256) void prep_kernel(const float* __restrict__ in,
                                                   u16* __restrict__ out,
                                                   const int* __restrict__ positions,
                                                   float* __restrict__ cosT,
                                                   float* __restrict__ sinT) {
    int b = blockIdx.x;
    if (b < 4096) {
        size_t i = ((size_t)b * 256 + threadIdx.x) * 8;
        float4 a = *(const float4*)&in[i];
        float4 c = *(const float4*)&in[i + 4];
        v8s tv;
        tv[0] = (short)f2bf(a.x); tv[1] = (short)f2bf(a.y);
        tv[2] = (short)f2bf(a.z); tv[3] = (short)f2bf(a.w);
        tv[4] = (short)f2bf(c.x); tv[5] = (short)f2bf(c.y);
        tv[6] = (short)f2bf(c.z); tv[7] = (short)f2bf(c.w);
        *(v8s*)&out[i] = tv;
    } else {
        int idx = (b - 4096) * 256 + threadIdx.x;   // T*64 entries
        int tp = idx >> 6, i = idx & 63;
        float invf = exp2f(-(float)i * 0.31143075889569023f);  // log2(1e6)/64
        float f = (float)positions[tp] * invf;
        cosT[idx] = cosf(f);
        sinT[idx] = sinf(f);
    }
}

// -------- transpose + cast: out[n][k] = bf16(in[k][n]) --------
__global__ __launch_bounds__(256) void transpose_cast_kernel(const float* __restrict__ in,
                                                             u16* __restrict__ out,
                                                             int K, int N) {
    __shared__ float tile[64][65];
    int n0 = blockIdx.x * 64, k0 = blockIdx.y * 64;
    int t = threadIdx.x;
    int rc = t >> 4;
    int cc = (t & 15) * 4;
#pragma unroll
    for (int p = 0; p < 4; ++p) {
        int k = p * 16 + rc;
        float4 v = *(const float4*)&in[(size_t)(k0 + k) * N + n0 + cc];
        tile[k][cc] = v.x; tile[k][cc + 1] = v.y;
        tile[k][cc + 2] = v.z; tile[k][cc + 3] = v.w;
    }
    __syncthreads();
    int rn = t >> 3;
    int ck = (t & 7) * 8;
#pragma unroll
    for (int p = 0; p < 2; ++p) {
        int n = p * 32 + rn;
        v8s tv;
#pragma unroll
        for (int j = 0; j < 8; ++j) tv[j] = (short)f2bf(tile[ck + j][n]);
        *(v8s*)&out[(size_t)(n0 + n) * K + k0 + ck] = tv;
    }
}

// ---------------- GEMM: C[M,:] = A[M,K]bf16 @ Bt[N,K]^T bf16 ----------------
// LDS staging XOR-swizzled: physical 16B-granule = logical ^ (row&7); the
// global SOURCE granule is permuted per lane (global_load_lds dest must stay
// lane*16), fragment ds_read_b128s then index granule^(l15&7) -> 2-way max.
// MODE 0: fp32 C store.  MODE 1: fused QK-norm + RoPE -> Q/K/Vt
//         (Q additionally pre-scaled by 1/sqrt(HD) so attn skips the scale mult).
template <int MODE>
__global__ __launch_bounds__(256) void gemm_bt_kernel(
    const u16* __restrict__ A, const u16* __restrict__ Bt, float* __restrict__ C, int N,
    const float* __restrict__ qw, const float* __restrict__ kw,
    const float* __restrict__ cosT, const float* __restrict__ sinT,
    u16* __restrict__ Qb, u16* __restrict__ Kb, u16* __restrict__ Vt)
{
    __shared__ __align__(16) u16 smem[16896];   // stage: A[128][64]+B[128][64]; epilogue: Ct[128][132]
    u16* As = smem;
    u16* Bs = smem + 8192;
    int tid = threadIdx.x;
    int wave = tid >> 6, lane = tid & 63;
    int quad = lane >> 4, l15 = lane & 15;
    int lm = l15 & 7;                 // read-side swizzle key
    int wm = wave >> 1, wn = wave & 1;
    int m0 = blockIdx.y * 128, n0 = blockIdx.x * 128;

    v4f acc[4][4];
    v4f z4 = {0.f, 0.f, 0.f, 0.f};
#pragma unroll
    for (int mi = 0; mi < 4; ++mi)
#pragma unroll
        for (int ni = 0; ni < 4; ++ni) acc[mi][ni] = z4;

    int rsub = lane >> 3;                       // row within 8-row chunk
    int cg = (lane & 7) ^ rsub;                 // swizzled source granule
    const u16* Ag = &A[(size_t)m0 * KD + cg * 8];
    const u16* Bg = &Bt[(size_t)n0 * KD + cg * 8];

    for (int k0 = 0; k0 < KD; k0 += 64) {
        __syncthreads();
#pragma unroll
        for (int c = 0; c < 4; ++c) {
            int ch = wave * 4 + c;
            int row = ch * 8 + rsub;
            gl2lds16(&Ag[(size_t)row * KD + k0], &As[ch * 512]);
            gl2lds16(&Bg[(size_t)row * KD + k0], &Bs[ch * 512]);
        }
        __syncthreads();
#pragma unroll
        for (int ks = 0; ks < 2; ++ks) {
            v8s af[4], bfr[4];
#pragma unroll
            for (int mi = 0; mi < 4; ++mi) {
                int ar = wm * 64 + mi * 16 + l15;
                af[mi] = *(const v8s*)&As[ar * 64 + ((((ks << 2) + quad) ^ lm) << 3)];
            }
#pragma unroll
            for (int ni = 0; ni < 4; ++ni) {
                int br = wn * 64 + ni * 16 + l15;
                bfr[ni] = *(const v8s*)&Bs[br * 64 + ((((ks << 2) + quad) ^ lm) << 3)];
            }
#pragma unroll
            for (int mi = 0; mi < 4; ++mi)
#pragma unroll
                for (int ni = 0; ni < 4; ++ni)
                    acc[mi][ni] = __builtin_amdgcn_mfma_f32_16x16x32_bf16(
                        af[mi], bfr[ni], acc[mi][ni], 0, 0, 0);
        }
    }

    if (MODE == 0) {
#pragma unroll
        for (int mi = 0; mi < 4; ++mi)
#pragma unroll
            for (int ni = 0; ni < 4; ++ni)
#pragma unroll
                for (int r = 0; r < 4; ++r)
                    C[(size_t)(m0 + wm * 64 + mi * 16 + quad * 4 + r) * N +
                      (n0 + wn * 64 + ni * 16 + l15)] = acc[mi][ni][r];
    } else {
        // ---- fused epilogue: this block's 128 cols == one head ----
        __syncthreads();
        u16* Ct = smem;   // [128][132] bf16, padded stride
#pragma unroll
        for (int mi = 0; mi < 4; ++mi)
#pragma unroll
            for (int ni = 0; ni < 4; ++ni)
#pragma unroll
                for (int r = 0; r < 4; ++r)
                    Ct[(wm * 64 + mi * 16 + quad * 4 + r) * 132 + wn * 64 + ni * 16 + l15] =
                        f2bf(acc[mi][ni][r]);
        __syncthreads();
        int head = blockIdx.x;    // 0..31 q, 32..39 k, 40..47 v
        int t0 = blockIdx.y * 128;
        if (head < 40) {
            if (tid < 128) {
                int row = tid;
                const float* w = (head < 32) ? qw : kw;
                float ss = 0.f;
                for (int i = 0; i < 128; ++i) {
                    float x = bf2f(Ct[row * 132 + i]);
                    ss += x * x;
                }
                float rs = rsqrtf(ss * (1.0f / 128.0f) + 1e-6f);
                if (head < 32) rs *= 0.08838834764831845f;   // fold 1/sqrt(HD) into Q
                int ti = t0 + row;
                for (int i = 0; i < 64; ++i) {
                    float x1 = bf2f(Ct[row * 132 + i]) * rs * w[i];
                    float x2 = bf2f(Ct[row * 132 + 64 + i]) * rs * w[64 + i];
                    float c = cosT[ti * 64 + i], s = sinT[ti * 64 + i];
                    Ct[row * 132 + i]      = f2bf(x1 * c - x2 * s);
                    Ct[row * 132 + 64 + i] = f2bf(x2 * c + x1 * s);
                }
            }
            __syncthreads();
            u16* dst = (head < 32) ? &Qb[((size_t)head * TT + t0) * HDM]
                                   : &Kb[((size_t)(head - 32) * TT + t0) * HDM];
            for (int cix = tid; cix < 128 * 16; cix += 256) {
                int row = cix >> 4, part = (cix & 15) * 8;
                v8s tv;
#pragma unroll
                for (int j = 0; j < 8; ++j) tv[j] = (short)Ct[row * 132 + part + j];
                *(v8s*)&dst[row * HDM + part] = tv;
            }
        } else {
            // V head: write transposed Vt[kv][hd][t]
            int kvh = head - 40;
            if (tid < 128) {
                int hd = tid;
#pragma unroll
                for (int tb = 0; tb < 16; ++tb) {
                    v8s tv;
#pragma unroll
                    for (int j = 0; j < 8; ++j) tv[j] = (short)Ct[(tb * 8 + j) * 132 + hd];
                    *(v8s*)&Vt[((size_t)kvh * HDM + hd) * TT + t0 + tb * 8] = tv;
                }
            }
        }
    }
}

// ---------------- flash attention (causal, GQA) ----------------
// 1D grid 1024, longest-first: qb = 31 - (idx>>5), h = idx&31.
// LDS layouts XOR-swizzled (phys 16B-chunk = logical ^ (row&7)) to kill
// the 16-way bank conflicts of power-of-2 row strides; gl2lds16 staging
// permutes the GLOBAL source address per lane (LDS dest must stay lane*16).
__global__ __launch_bounds__(256) void attn_kernel(
    const u16* __restrict__ Qb, const u16* __restrict__ Kb,
    const u16* __restrict__ Vt, u16* __restrict__ Ob)
{
    __shared__ __align__(16) u16 Kl[64 * 128];   // [s][hd] swizzled, 16 chunks/row
    __shared__ __align__(16) u16 Vl[128 * 64];   // [hd][s] swizzled, 8 chunks/row
    __shared__ __align__(16) u16 Pl[4 * 16 * 64];  // per-wave P, swizzled, 8 chunks/row
    int tid = threadIdx.x;
    int wave = tid >> 6, lane = tid & 63;
    int quad = lane >> 4, l15 = lane & 15;
    int idx = blockIdx.x;
    int h = idx & 31;
    int qb = 31 - (idx >> 5);        // longest blocks dispatch first
    int kv = h >> 2;                 // H/KV = 4
    int q0 = qb * 64;
    int lm = l15 & 7;                // swizzle mask for this lane's row group

    v8s qf[4];
    {
        const u16* qr = &Qb[((size_t)h * TT + q0 + wave * 16 + l15) * HDM];
#pragma unroll
        for (int ks = 0; ks < 4; ++ks) qf[ks] = *(const v8s*)&qr[ks * 32 + quad * 8];
    }

    v4f z4 = {0.f, 0.f, 0.f, 0.f};
    v4f of[8];
#pragma unroll
    for (int i = 0; i < 8; ++i) of[i] = z4;
    float mold[4], lsum[4];
#pragma unroll
    for (int r = 0; r < 4; ++r) { mold[r] = -3.0e38f; lsum[r] = 0.f; }
    u16* Pw = &Pl[wave * 1024];

    for (int s0 = 0; s0 <= q0; s0 += 64) {
        __syncthreads();
#pragma unroll
        for (int c = 0; c < 4; ++c) {
            int ch = wave * 4 + c;
            int rk = ch * 4 + (lane >> 4);              // Kl row (s-local)
            int ck = (lane & 15) ^ (rk & 7);            // logical chunk to fetch
            gl2lds16(&Kb[((size_t)kv * TT + s0 + rk) * HDM + ck * 8], &Kl[ch * 512]);
            int rv = ch * 8 + (lane >> 3);              // Vl row (hd)
            int cv = (lane & 7) ^ (rv & 7);
            gl2lds16(&Vt[((size_t)kv * HDM + rv) * TT + s0 + cv * 8], &Vl[ch * 512]);
        }
        __syncthreads();
        // S = Q @ K^T  (C-layout: row=quad*4+r, col=l15 within n-tile)
        v4f sf[4];
#pragma unroll
        for (int nt = 0; nt < 4; ++nt) {
            v4f cacc = z4;
#pragma unroll
            for (int ks = 0; ks < 4; ++ks)
                cacc = __builtin_amdgcn_mfma_f32_16x16x32_bf16(
                    qf[ks],
                    *(const v8s*)&Kl[(nt * 16 + l15) * 128 + (((ks * 4 + quad) ^ lm) << 3)],
                    cacc, 0, 0, 0);
            sf[nt] = cacc;
        }
        if (s0 == q0) {   // only the diagonal tile needs the causal mask
#pragma unroll
            for (int nt = 0; nt < 4; ++nt) {
                int sg = s0 + nt * 16 + l15;
#pragma unroll
                for (int r = 0; r < 4; ++r) {
                    int qg = q0 + wave * 16 + quad * 4 + r;
                    if (sg > qg) sf[nt][r] = -3.0e38f;
                }
            }
        }
        float mrow[4];
#pragma unroll
        for (int r = 0; r < 4; ++r) mrow[r] = -3.0e38f;
#pragma unroll
        for (int nt = 0; nt < 4; ++nt)
#pragma unroll
            for (int r = 0; r < 4; ++r) mrow[r] = fmaxf(mrow[r], sf[nt][r]);
#pragma unroll
        for (int off = 1; off < 16; off <<= 1)
#pragma unroll
            for (int r = 0; r < 4; ++r)
                mrow[r] = fmaxf(mrow[r], __shfl_xor(mrow[r], off, 64));
        float alpha[4], lrow[4];
#pragma unroll
        for (int r = 0; r < 4; ++r) {
            float mn = fmaxf(mold[r], mrow[r]);
            alpha[r] = __expf(mold[r] - mn);
            mold[r] = mn;
            lrow[r] = 0.f;
        }
#pragma unroll
        for (int nt = 0; nt < 4; ++nt)
#pragma unroll
            for (int r = 0; r < 4; ++r) {
                float p = __expf(sf[nt][r] - mold[r]);
                sf[nt][r] = p;
                lrow[r] += p;
            }
#pragma unroll
        for (int off = 1; off < 16; off <<= 1)
#pragma unroll
            for (int r = 0; r < 4; ++r) lrow[r] += __shfl_xor(lrow[r], off, 64);
#pragma unroll
        for (int r = 0; r < 4; ++r) lsum[r] = lsum[r] * alpha[r] + lrow[r];
        // P: C-layout -> swizzled LDS (A-layout source for PV)
#pragma unroll
        for (int nt = 0; nt < 4; ++nt)
#pragma unroll
            for (int r = 0; r < 4; ++r) {
                int row = quad * 4 + r;
                int pch = ((nt << 1) + (l15 >> 3)) ^ (row & 7);
                Pw[row * 64 + pch * 8 + (l15 & 7)] = f2bf(sf[nt][r]);
            }
        // rescale O
#pragma unroll
        for (int i = 0; i < 8; ++i)
#pragma unroll
            for (int r = 0; r < 4; ++r) of[i][r] *= alpha[r];
        // O += P @ V
#pragma unroll
        for (int sub = 0; sub < 2; ++sub) {
            v8s pa = *(const v8s*)&Pw[l15 * 64 + ((((sub << 2) + quad) ^ lm) << 3)];
#pragma unroll
            for (int nt = 0; nt < 8; ++nt)
                of[nt] = __builtin_amdgcn_mfma_f32_16x16x32_bf16(
                    pa,
                    *(const v8s*)&Vl[(nt * 16 + l15) * 64 + ((((sub << 2) + quad) ^ lm) << 3)],
                    of[nt], 0, 0, 0);
        }
    }
    float invl[4];
#pragma unroll
    for (int r = 0; r < 4; ++r) invl[r] = 1.0f / lsum[r];
#pragma unroll
    for (int nt = 0; nt < 8; ++nt)
#pragma unroll
        for (int r = 0; r < 4; ++r)
            Ob[(size_t)(q0 + wave * 16 + quad * 4 + r) * (NH * HDM) + h * HDM + nt * 16 + l15] =
                f2bf(of[nt][r] * invl[r]);
}

extern "C" void kernel_launch(void* const* d_in, const int* in_sizes, int n_in,
                              void* d_out, int out_size, void* d_ws, size_t ws_size,
                              hipStream_t stream)
{
    (void)in_sizes; (void)n_in; (void)out_size; (void)ws_size;
    const int*   positions = (const int*)d_in[0];
    const float* hidden    = (const float*)d_in[1];
    const float* w_qkv     = (const float*)d_in[2];
    const float* q_norm_w  = (const float*)d_in[3];
    const float* k_norm_w  = (const float*)d_in[4];
    const float* w_o       = (const float*)d_in[5];
    float* out = (float*)d_out;
    char* ws = (char*)d_ws;
    char* ob = (char*)d_out;

    // ---- d_ws layout (peak = 64 MiB exactly) ----
    u16* hid_bf = (u16*)(ws + 0);                 // [2048][4096] bf16      16 MiB
    u16* attnO  = (u16*)(ws + 0);                 // aliases hid_bf (dead after QKV GEMM)
    u16* wqkv_t = (u16*)(ws + (size_t)16777216);  // [6144][4096] bf16      50.33 MiB (ends at 64 MiB)
    u16* wo_t   = (u16*)(ws + (size_t)16777216);  // [4096][4096] bf16, overwrites wqkv_t after QKV GEMM

    // ---- d_out-hosted scratch (26.2 MiB <= 32 MiB; all dead before final GEMM) ----
    u16*   Qb   = (u16*)(ob + 0);                 // [32][2048][128]     16 MiB
    u16*   Kb   = (u16*)(ob + (size_t)16777216);  // [8][2048][128]      4 MiB
    u16*   Vt   = (u16*)(ob + (size_t)20971520);  // [8][128][2048]      4 MiB
    float* cosT = (float*)(ob + (size_t)25165824);// [2048][64]          0.5 MiB
    float* sinT = (float*)(ob + (size_t)25690112);// [2048][64]          0.5 MiB

    // cast hidden -> bf16 + build RoPE tables (one launch)
    prep_kernel<<<4608, 256, 0, stream>>>(hidden, hid_bf, positions, cosT, sinT);

    // full w_qkv transpose+cast, then single fused QKV GEMM (768 blocks = 3/CU)
    transpose_cast_kernel<<<dim3(96, 64), 256, 0, stream>>>(w_qkv, wqkv_t, 4096, NQKV);
    gemm_bt_kernel<1><<<dim3(48, 16), 256, 0, stream>>>(
        hid_bf, wqkv_t, nullptr, NQKV, q_norm_w, k_norm_w, cosT, sinT, Qb, Kb, Vt);

    // attention: reads Qb/Kb/Vt (d_out), writes attnO (ws, aliases hid_bf)
    attn_kernel<<<dim3(1024), 256, 0, stream>>>(Qb, Kb, Vt, attnO);

    // out-proj: w_o -> wo_t (reuses wqkv_t region), GEMM writes fp32 over all of d_out
    transpose_cast_kernel<<<dim3(64, 64), 256, 0, stream>>>(w_o, wo_t, 4096, 4096);
    gemm_bt_kernel<0><<<dim3(32, 16), 256, 0, stream>>>(
        attnO, wo_t, out, 4096, nullptr, nullptr, nullptr, nullptr, nullptr, nullptr, nullptr);
}

// Round 6
// 487.109 us; speedup vs baseline: 1.6243x; 1.0508x over previous
//
#include <hip/hip_runtime.h>

#define TT   2048
#define DD   4096
#define NH   32
#define NKVH 8
#define HDM  128
#define KD   4096
#define NQKV 6144

typedef unsigned short u16;
typedef short v8s __attribute__((ext_vector_type(8)));
typedef float v4f __attribute__((ext_vector_type(4)));

// Q pre-scale: 1/sqrt(128) * log2(e)  (log2e folded so attn uses bare exp2)
#define QSCALE 0.12751744547734565f
// fixed softmax max: 12 * log2(e). Valid because |S| <= |q||k|/sqrt(128) = 11.32
// (RMSNorm fixes |q|=|k|=sqrt(128); RoPE is a rotation, norm-preserving).
#define EOFF   17.312340490667562f

__device__ __forceinline__ u16 f2bf(float f) {
    unsigned u = __builtin_bit_cast(unsigned, f);
    u += 0x7fffu + ((u >> 16) & 1u);   // round-to-nearest-even
    return (u16)(u >> 16);
}
__device__ __forceinline__ float bf2f(u16 h) {
    return __builtin_bit_cast(float, ((unsigned)h) << 16);
}
__device__ __forceinline__ void gl2lds16(const void* g, void* l) {
    // async global->LDS, 16B/lane; LDS dest = wave-uniform base + lane*16
    using gv = const __attribute__((address_space(1))) void;
    using lv = __attribute__((address_space(3))) void;
    __builtin_amdgcn_global_load_lds((gv*)g, (lv*)l, 16, 0, 0);
}

// -------- 64x64 transpose+cast tile: out[n][k] = bf16(in[k][n]) --------
__device__ __forceinline__ void transpose_tile64(const float* __restrict__ in,
                                                 u16* __restrict__ out,
                                                 int K, int N, int n0, int k0,
                                                 float* tile, int t) {
    int rc = t >> 4, cc = (t & 15) * 4;
#pragma unroll
    for (int p = 0; p < 4; ++p) {
        int k = p * 16 + rc;
        float4 v = *(const float4*)&in[(size_t)(k0 + k) * N + n0 + cc];
        tile[k * 65 + cc] = v.x; tile[k * 65 + cc + 1] = v.y;
        tile[k * 65 + cc + 2] = v.z; tile[k * 65 + cc + 3] = v.w;
    }
    __syncthreads();
    int rn = t >> 3, ck = (t & 7) * 8;
#pragma unroll
    for (int p = 0; p < 2; ++p) {
        int n = p * 32 + rn;
        v8s tv;
#pragma unroll
        for (int j = 0; j < 8; ++j) tv[j] = (short)f2bf(tile[(ck + j) * 65 + n]);
        *(v8s*)&out[(size_t)(n0 + n) * K + k0 + ck] = tv;
    }
}

// ------- prep_all: hidden cast (0..4095) + RoPE tab (4096..4607) + w_qkv^T (4608..10751) -------
__global__ __launch_bounds__(256) void prep_all_kernel(const float* __restrict__ hidden,
                                                       u16* __restrict__ hid_bf,
                                                       const int* __restrict__ positions,
                                                       float* __restrict__ cosT,
                                                       float* __restrict__ sinT,
                                                       const float* __restrict__ w_qkv,
                                                       u16* __restrict__ wqkv_t) {
    __shared__ float tile[64 * 65];
    int b = blockIdx.x;
    if (b < 4096) {
        size_t i = ((size_t)b * 256 + threadIdx.x) * 8;
        float4 a = *(const float4*)&hidden[i];
        float4 c = *(const float4*)&hidden[i + 4];
        v8s tv;
        tv[0] = (short)f2bf(a.x); tv[1] = (short)f2bf(a.y);
        tv[2] = (short)f2bf(a.z); tv[3] = (short)f2bf(a.w);
        tv[4] = (short)f2bf(c.x); tv[5] = (short)f2bf(c.y);
        tv[6] = (short)f2bf(c.z); tv[7] = (short)f2bf(c.w);
        *(v8s*)&hid_bf[i] = tv;
    } else if (b < 4608) {
        int idx = (b - 4096) * 256 + threadIdx.x;   // T*64 entries
        int tp = idx >> 6, i = idx & 63;
        float invf = exp2f(-(float)i * 0.31143075889569023f);  // log2(1e6)/64
        float f = (float)positions[tp] * invf;
        cosT[idx] = cosf(f);
        sinT[idx] = sinf(f);
    } else {
        int bx = b - 4608;                    // 96 x 64 tiles
        int n0 = (bx % 96) * 64, k0 = (bx / 96) * 64;
        transpose_tile64(w_qkv, wqkv_t, 4096, NQKV, n0, k0, tile, threadIdx.x);
    }
}

// ---------------- GEMM: C[M,:] = A[M,K]bf16 @ Bt[N,K]^T bf16 ----------------
// LDS staging XOR-swizzled: physical 16B-granule = logical ^ (row&7); the
// global SOURCE granule is permuted per lane (global_load_lds dest must stay
// lane*16), fragment ds_read_b128s then index granule^(l15&7) -> 2-way max.
// MODE 0: fp32 C store.  MODE 1: fused QK-norm + RoPE -> Q/K/Vt
//         (Q pre-scaled by QSCALE = 1/sqrt(HD)*log2e for the attn exp2 path).
template <int MODE>
__global__ __launch_bounds__(256) void gemm_bt_kernel(
    const u16* __restrict__ A, const u16* __restrict__ Bt, float* __restrict__ C, int N,
    const float* __restrict__ qw, const float* __restrict__ kw,
    const float* __restrict__ cosT, const float* __restrict__ sinT,
    u16* __restrict__ Qb, u16* __restrict__ Kb, u16* __restrict__ Vt)
{
    __shared__ __align__(16) u16 smem[16896];   // stage: A[128][64]+B[128][64]; epilogue: Ct[128][132]
    u16* As = smem;
    u16* Bs = smem + 8192;
    int tid = threadIdx.x;
    int wave = tid >> 6, lane = tid & 63;
    int quad = lane >> 4, l15 = lane & 15;
    int lm = l15 & 7;                 // read-side swizzle key
    int wm = wave >> 1, wn = wave & 1;
    int m0 = blockIdx.y * 128, n0 = blockIdx.x * 128;

    v4f acc[4][4];
    v4f z4 = {0.f, 0.f, 0.f, 0.f};
#pragma unroll
    for (int mi = 0; mi < 4; ++mi)
#pragma unroll
        for (int ni = 0; ni < 4; ++ni) acc[mi][ni] = z4;

    int rsub = lane >> 3;                       // row within 8-row chunk
    int cg = (lane & 7) ^ rsub;                 // swizzled source granule
    const u16* Ag = &A[(size_t)m0 * KD + cg * 8];
    const u16* Bg = &Bt[(size_t)n0 * KD + cg * 8];

    for (int k0 = 0; k0 < KD; k0 += 64) {
        __syncthreads();
#pragma unroll
        for (int c = 0; c < 4; ++c) {
            int ch = wave * 4 + c;
            int row = ch * 8 + rsub;
            gl2lds16(&Ag[(size_t)row * KD + k0], &As[ch * 512]);
            gl2lds16(&Bg[(size_t)row * KD + k0], &Bs[ch * 512]);
        }
        __syncthreads();
#pragma unroll
        for (int ks = 0; ks < 2; ++ks) {
            v8s af[4], bfr[4];
#pragma unroll
            for (int mi = 0; mi < 4; ++mi) {
                int ar = wm * 64 + mi * 16 + l15;
                af[mi] = *(const v8s*)&As[ar * 64 + ((((ks << 2) + quad) ^ lm) << 3)];
            }
#pragma unroll
            for (int ni = 0; ni < 4; ++ni) {
                int br = wn * 64 + ni * 16 + l15;
                bfr[ni] = *(const v8s*)&Bs[br * 64 + ((((ks << 2) + quad) ^ lm) << 3)];
            }
#pragma unroll
            for (int mi = 0; mi < 4; ++mi)
#pragma unroll
                for (int ni = 0; ni < 4; ++ni)
                    acc[mi][ni] = __builtin_amdgcn_mfma_f32_16x16x32_bf16(
                        af[mi], bfr[ni], acc[mi][ni], 0, 0, 0);
        }
    }

    if (MODE == 0) {
#pragma unroll
        for (int mi = 0; mi < 4; ++mi)
#pragma unroll
            for (int ni = 0; ni < 4; ++ni)
#pragma unroll
                for (int r = 0; r < 4; ++r)
                    C[(size_t)(m0 + wm * 64 + mi * 16 + quad * 4 + r) * N +
                      (n0 + wn * 64 + ni * 16 + l15)] = acc[mi][ni][r];
    } else {
        // ---- fused epilogue: this block's 128 cols == one head ----
        __syncthreads();
        u16* Ct = smem;   // [128][132] bf16, padded stride
#pragma unroll
        for (int mi = 0; mi < 4; ++mi)
#pragma unroll
            for (int ni = 0; ni < 4; ++ni)
#pragma unroll
                for (int r = 0; r < 4; ++r)
                    Ct[(wm * 64 + mi * 16 + quad * 4 + r) * 132 + wn * 64 + ni * 16 + l15] =
                        f2bf(acc[mi][ni][r]);
        __syncthreads();
        int head = blockIdx.x;    // 0..31 q, 32..39 k, 40..47 v
        int t0 = blockIdx.y * 128;
        if (head < 40) {
            if (tid < 128) {
                int row = tid;
                const float* w = (head < 32) ? qw : kw;
                float ss = 0.f;
                for (int i = 0; i < 128; ++i) {
                    float x = bf2f(Ct[row * 132 + i]);
                    ss += x * x;
                }
                float rs = rsqrtf(ss * (1.0f / 128.0f) + 1e-6f);
                if (head < 32) rs *= QSCALE;   // fold 1/sqrt(HD)*log2e into Q
                int ti = t0 + row;
                for (int i = 0; i < 64; ++i) {
                    float x1 = bf2f(Ct[row * 132 + i]) * rs * w[i];
                    float x2 = bf2f(Ct[row * 132 + 64 + i]) * rs * w[64 + i];
                    float c = cosT[ti * 64 + i], s = sinT[ti * 64 + i];
                    Ct[row * 132 + i]      = f2bf(x1 * c - x2 * s);
                    Ct[row * 132 + 64 + i] = f2bf(x2 * c + x1 * s);
                }
            }
            __syncthreads();
            u16* dst = (head < 32) ? &Qb[((size_t)head * TT + t0) * HDM]
                                   : &Kb[((size_t)(head - 32) * TT + t0) * HDM];
            for (int cix = tid; cix < 128 * 16; cix += 256) {
                int row = cix >> 4, part = (cix & 15) * 8;
                v8s tv;
#pragma unroll
                for (int j = 0; j < 8; ++j) tv[j] = (short)Ct[row * 132 + part + j];
                *(v8s*)&dst[row * HDM + part] = tv;
            }
        } else {
            // V head: write transposed Vt[kv][hd][t]
            int kvh = head - 40;
            if (tid < 128) {
                int hd = tid;
#pragma unroll
                for (int tb = 0; tb < 16; ++tb) {
                    v8s tv;
#pragma unroll
                    for (int j = 0; j < 8; ++j) tv[j] = (short)Ct[(tb * 8 + j) * 132 + hd];
                    *(v8s*)&Vt[((size_t)kvh * HDM + hd) * TT + t0 + tb * 8] = tv;
                }
            }
        }
    }
}

// ------- attn (blocks 0..1023) + w_o transpose backfill (1024..5119) -------
// attn: fixed-max flash attention (no running max: S*log2e <= 16.34 < EOFF),
// per-lane l-sum with single end-of-kernel cross-lane reduction.
// 1D longest-first: qb = 31 - (idx>>5), h = idx&31. LDS XOR-swizzled.
__global__ __launch_bounds__(256) void attn_plus_kernel(
    const u16* __restrict__ Qb, const u16* __restrict__ Kb,
    const u16* __restrict__ Vt, u16* __restrict__ Ob,
    const float* __restrict__ w_o, u16* __restrict__ wo_t)
{
    __shared__ __align__(16) char smem_raw[40960];
    int tid = threadIdx.x;
    if (blockIdx.x >= 1024) {
        int bx = blockIdx.x - 1024;           // 64 x 64 tiles
        int n0 = (bx & 63) * 64, k0 = (bx >> 6) * 64;
        transpose_tile64(w_o, wo_t, 4096, 4096, n0, k0, (float*)smem_raw, tid);
        return;
    }
    u16* Kl = (u16*)smem_raw;                  // [s][hd] swizzled, 16384 B
    u16* Vl = (u16*)(smem_raw + 16384);        // [hd][s] swizzled, 16384 B
    u16* Pl = (u16*)(smem_raw + 32768);        // per-wave P, swizzled, 8192 B
    int wave = tid >> 6, lane = tid & 63;
    int quad = lane >> 4, l15 = lane & 15;
    int idx = blockIdx.x;
    int h = idx & 31;
    int qb = 31 - (idx >> 5);        // longest blocks dispatch first
    int kv = h >> 2;                 // H/KV = 4
    int q0 = qb * 64;
    int lm = l15 & 7;                // swizzle mask for this lane's row group

    v8s qf[4];
    {
        const u16* qr = &Qb[((size_t)h * TT + q0 + wave * 16 + l15) * HDM];
#pragma unroll
        for (int ks = 0; ks < 4; ++ks) qf[ks] = *(const v8s*)&qr[ks * 32 + quad * 8];
    }

    v4f z4 = {0.f, 0.f, 0.f, 0.f};
    v4f of[8];
#pragma unroll
    for (int i = 0; i < 8; ++i) of[i] = z4;
    float lsum[4];
#pragma unroll
    for (int r = 0; r < 4; ++r) lsum[r] = 0.f;
    u16* Pw = &Pl[wave * 1024];

    for (int s0 = 0; s0 <= q0; s0 += 64) {
        __syncthreads();
#pragma unroll
        for (int c = 0; c < 4; ++c) {
            int ch = wave * 4 + c;
            int rk = ch * 4 + (lane >> 4);              // Kl row (s-local)
            int ck = (lane & 15) ^ (rk & 7);            // logical chunk to fetch
            gl2lds16(&Kb[((size_t)kv * TT + s0 + rk) * HDM + ck * 8], &Kl[ch * 512]);
            int rv = ch * 8 + (lane >> 3);              // Vl row (hd)
            int cv = (lane & 7) ^ (rv & 7);
            gl2lds16(&Vt[((size_t)kv * HDM + rv) * TT + s0 + cv * 8], &Vl[ch * 512]);
        }
        __syncthreads();
        // S = Q @ K^T  (C-layout: row=quad*4+r, col=l15 within n-tile)
        v4f sf[4];
#pragma unroll
        for (int nt = 0; nt < 4; ++nt) {
            v4f cacc = z4;
#pragma unroll
            for (int ks = 0; ks < 4; ++ks)
                cacc = __builtin_amdgcn_mfma_f32_16x16x32_bf16(
                    qf[ks],
                    *(const v8s*)&Kl[(nt * 16 + l15) * 128 + (((ks * 4 + quad) ^ lm) << 3)],
                    cacc, 0, 0, 0);
            sf[nt] = cacc;
        }
        if (s0 == q0) {   // only the diagonal tile needs the causal mask
#pragma unroll
            for (int nt = 0; nt < 4; ++nt) {
                int sg = s0 + nt * 16 + l15;
#pragma unroll
                for (int r = 0; r < 4; ++r) {
                    int qg = q0 + wave * 16 + quad * 4 + r;
                    if (sg > qg) sf[nt][r] = -3.0e38f;
                }
            }
        }
        // fixed-max softmax: p = exp2(S*log2e - 12*log2e); masked -> exp2(-inf)=0
#pragma unroll
        for (int nt = 0; nt < 4; ++nt)
#pragma unroll
            for (int r = 0; r < 4; ++r) {
                float p = exp2f(sf[nt][r] - EOFF);
                sf[nt][r] = p;
                lsum[r] += p;
            }
        // P: C-layout -> swizzled LDS (A-layout source for PV)
#pragma unroll
        for (int nt = 0; nt < 4; ++nt)
#pragma unroll
            for (int r = 0; r < 4; ++r) {
                int row = quad * 4 + r;
                int pch = ((nt << 1) + (l15 >> 3)) ^ (row & 7);
                Pw[row * 64 + pch * 8 + (l15 & 7)] = f2bf(sf[nt][r]);
            }
        // O += P @ V  (no rescale needed with fixed max)
#pragma unroll
        for (int sub = 0; sub < 2; ++sub) {
            v8s pa = *(const v8s*)&Pw[l15 * 64 + ((((sub << 2) + quad) ^ lm) << 3)];
#pragma unroll
            for (int nt = 0; nt < 8; ++nt)
                of[nt] = __builtin_amdgcn_mfma_f32_16x16x32_bf16(
                    pa,
                    *(const v8s*)&Vl[(nt * 16 + l15) * 64 + ((((sub << 2) + quad) ^ lm) << 3)],
                    of[nt], 0, 0, 0);
        }
    }
    // single end-of-kernel l reduction across the 16 col-lanes (same quad group)
#pragma unroll
    for (int off = 1; off < 16; off <<= 1)
#pragma unroll
        for (int r = 0; r < 4; ++r) lsum[r] += __shfl_xor(lsum[r], off, 64);
    float invl[4];
#pragma unroll
    for (int r = 0; r < 4; ++r) invl[r] = 1.0f / lsum[r];
#pragma unroll
    for (int nt = 0; nt < 8; ++nt)
#pragma unroll
        for (int r = 0; r < 4; ++r)
            Ob[(size_t)(q0 + wave * 16 + quad * 4 + r) * (NH * HDM) + h * HDM + nt * 16 + l15] =
                f2bf(of[nt][r] * invl[r]);
}

extern "C" void kernel_launch(void* const* d_in, const int* in_sizes, int n_in,
                              void* d_out, int out_size, void* d_ws, size_t ws_size,
                              hipStream_t stream)
{
    (void)in_sizes; (void)n_in; (void)out_size; (void)ws_size;
    const int*   positions = (const int*)d_in[0];
    const float* hidden    = (const float*)d_in[1];
    const float* w_qkv     = (const float*)d_in[2];
    const float* q_norm_w  = (const float*)d_in[3];
    const float* k_norm_w  = (const float*)d_in[4];
    const float* w_o       = (const float*)d_in[5];
    float* out = (float*)d_out;
    char* ws = (char*)d_ws;
    char* ob = (char*)d_out;

    // ---- d_ws layout (peak = 64 MiB exactly) ----
    u16* hid_bf = (u16*)(ws + 0);                 // [2048][4096] bf16      16 MiB
    u16* attnO  = (u16*)(ws + 0);                 // aliases hid_bf (dead after QKV GEMM)
    u16* wqkv_t = (u16*)(ws + (size_t)16777216);  // [6144][4096] bf16      50.33 MiB (ends at 64 MiB)
    u16* wo_t   = (u16*)(ws + (size_t)16777216);  // [4096][4096] bf16, overwrites wqkv_t after QKV GEMM

    // ---- d_out-hosted scratch (26.2 MiB <= 32 MiB; all dead before final GEMM) ----
    u16*   Qb   = (u16*)(ob + 0);                 // [32][2048][128]     16 MiB
    u16*   Kb   = (u16*)(ob + (size_t)16777216);  // [8][2048][128]      4 MiB
    u16*   Vt   = (u16*)(ob + (size_t)20971520);  // [8][128][2048]      4 MiB
    float* cosT = (float*)(ob + (size_t)25165824);// [2048][64]          0.5 MiB
    float* sinT = (float*)(ob + (size_t)25690112);// [2048][64]          0.5 MiB

    // hidden cast + RoPE tables + w_qkv transpose, one launch
    prep_all_kernel<<<10752, 256, 0, stream>>>(hidden, hid_bf, positions, cosT, sinT,
                                               w_qkv, wqkv_t);

    // single fused QKV GEMM (768 blocks = 3/CU)
    gemm_bt_kernel<1><<<dim3(48, 16), 256, 0, stream>>>(
        hid_bf, wqkv_t, nullptr, NQKV, q_norm_w, k_norm_w, cosT, sinT, Qb, Kb, Vt);

    // attention (1024 blocks) + w_o transpose backfill (4096 blocks), one launch
    attn_plus_kernel<<<5120, 256, 0, stream>>>(Qb, Kb, Vt, attnO, w_o, wo_t);

    // out-proj GEMM writes fp32 over all of d_out
    gemm_bt_kernel<0><<<dim3(32, 16), 256, 0, stream>>>(
        attnO, wo_t, out, 4096, nullptr, nullptr, nullptr, nullptr, nullptr, nullptr, nullptr);
}